// Round 10
// baseline (36.255 us; speedup 1.0000x reference)
//
#include <hip/hip_runtime.h>
#include <math.h>

#define DD   768
#define BB   32
#define NTP  256        // target pixels per batch (16x16)
#define NSP  1024       // search pixels per batch (32x32)
#define NT   (BB*NTP)   // 8192 target px
#define NS   (BB*NSP)   // 32768 search px
#define ECH  32         // E-chunks for prep (24 rows each)
#define CHE  (DD/ECH)   // 24
#define NSL  8          // search channel slices (96 ch)
#define NTL  2          // target channel slices (384 ch)

// ws layout (floats); float4-aligned offsets
#define OFF_UP  0                      // uPart[ECH][DD]
#define OFF_VP  (OFF_UP + ECH*DD)      // vPart[ECH][DD]
#define OFF_K   (OFF_VP + ECH*DD)      // K1,K2 (+pad)
#define OFF_TR0 (OFF_K + 64)           // target R dots [NTL][NT]
#define OFF_TS0 (OFF_TR0 + NTL*NT)     // target S dots [NTL][NT]
#define OFF_SR  (OFF_TS0 + NTL*NT)     // search R dots [NSL][NS]
#define OFF_SS  (OFF_SR + NSL*NS)      // search S dots [NSL][NS]
// total ~ 606K floats ~= 2.4 MB

#define A5 0.99500999000499900f        // (1 - LR*LAMBDA)^5

// 33 blocks: 32 compute U/V partials over 24-row chunks of w; 1 computes K1/K2.
__global__ void k_prep(const float* __restrict__ w, const float* __restrict__ cb,
                       const float* __restrict__ gamma, const float* __restrict__ beta,
                       const float* __restrict__ mean, const float* __restrict__ var,
                       const float* __restrict__ fi, float* __restrict__ ws) {
    int bx = blockIdx.x;
    int t = threadIdx.x;
    if (bx < ECH) {
        __shared__ float wu[CHE], wv[CHE];
        if (t < CHE) {
            int e = bx * CHE + t;
            float inv = gamma[e] / sqrtf(var[e] + 1e-5f);
            wv[t] = inv;
            wu[t] = inv * fi[e];
        }
        __syncthreads();
        if (t < 192) {   // one f4-column (4 d's) per thread
            const float4* w4 = (const float4*)w;
            float4 Ru = {0,0,0,0}, Rv = {0,0,0,0};
            #pragma unroll
            for (int j = 0; j < CHE; ++j) {
                float4 x = w4[(size_t)(bx * CHE + j) * 192 + t];
                float a = wu[j], b = wv[j];
                Ru.x += x.x * a; Ru.y += x.y * a; Ru.z += x.z * a; Ru.w += x.w * a;
                Rv.x += x.x * b; Rv.y += x.y * b; Rv.z += x.z * b; Rv.w += x.w * b;
            }
            *(float4*)(ws + OFF_UP + bx * DD + t * 4) = Ru;
            *(float4*)(ws + OFF_VP + bx * DD + t * 4) = Rv;
        }
    } else {
        __shared__ float r1[256], r2[256];
        float a1 = 0.f, a2 = 0.f;
        for (int e = t; e < DD; e += 256) {
            float inv = gamma[e] / sqrtf(var[e] + 1e-5f);
            float x = (cb[e] - mean[e]) * inv + beta[e];
            a1 += x * fi[e];
            a2 += x;
        }
        r1[t] = a1; r2[t] = a2;
        __syncthreads();
        for (int s = 128; s > 0; s >>= 1) {
            if (t < s) { r1[t] += r1[t + s]; r2[t] += r2[t + s]; }
            __syncthreads();
        }
        if (t == 0) { ws[OFF_K] = r1[0]; ws[OFF_K + 1] = r2[0]; }
    }
}

// 320 blocks, each streams one DENSE CONTIGUOUS 384 KB region:
//   0..255 : search, b = bx>>3, slice = bx&7 (96 ch x 1024 px)
//   256..319: target, b = (bx-256)>>1, slice = (bx-256)&1 (384 ch x 256 px)
// Flat f4 mapping idx = t + i*256 (96 iters): search threads own pixel-quad t
// for ALL channels (private accumulate, no reduce); target threads own pixel
// (t&63) for channel-group (t>>6)+4i (4-way LDS reduce).
__global__ __launch_bounds__(256) void k_big(const float* __restrict__ sf,
                                             const float* __restrict__ tf,
                                             float* __restrict__ ws) {
    int bx = blockIdx.x;
    int t = threadIdx.x;
    bool isS = bx < 256;
    int b, slice;
    if (isS) { b = bx >> 3; slice = bx & 7; }
    else     { int u = bx - 256; b = u >> 1; slice = u & 1; }

    __shared__ float su[384], sv[384];
    if (isS) {
        // 96-ch slice: f4-cols [slice*24, slice*24+24)
        if (t < 24) {
            float4 U = {0,0,0,0};
            #pragma unroll
            for (int ec = 0; ec < ECH; ++ec) {
                float4 a = ((const float4*)(ws + OFF_UP))[ec * 192 + slice * 24 + t];
                U.x += a.x; U.y += a.y; U.z += a.z; U.w += a.w;
            }
            ((float4*)su)[t] = U;
        } else if (t < 48) {
            int j = t - 24;
            float4 V = {0,0,0,0};
            #pragma unroll
            for (int ec = 0; ec < ECH; ++ec) {
                float4 c = ((const float4*)(ws + OFF_VP))[ec * 192 + slice * 24 + j];
                V.x += c.x; V.y += c.y; V.z += c.z; V.w += c.w;
            }
            ((float4*)sv)[j] = V;
        }
    } else {
        // 384-ch slice: f4-cols [slice*96, slice*96+96)
        if (t < 96) {
            float4 U = {0,0,0,0};
            #pragma unroll
            for (int ec = 0; ec < ECH; ++ec) {
                float4 a = ((const float4*)(ws + OFF_UP))[ec * 192 + slice * 96 + t];
                U.x += a.x; U.y += a.y; U.z += a.z; U.w += a.w;
            }
            ((float4*)su)[t] = U;
        } else if (t < 192) {
            int j = t - 96;
            float4 V = {0,0,0,0};
            #pragma unroll
            for (int ec = 0; ec < ECH; ++ec) {
                float4 c = ((const float4*)(ws + OFF_VP))[ec * 192 + slice * 96 + j];
                V.x += c.x; V.y += c.y; V.z += c.z; V.w += c.w;
            }
            ((float4*)sv)[j] = V;
        }
    }
    __syncthreads();

    float4 accR = {0,0,0,0}, accS = {0,0,0,0};
    if (isS) {
        const float4* base = (const float4*)sf + ((size_t)b * DD + slice * 96) * (NSP/4) + t;
        float4 buf[12];
        #pragma unroll
        for (int k = 0; k < 12; ++k) buf[k] = base[(size_t)k * 256];
        #pragma unroll
        for (int i = 0; i < 96; ++i) {
            float4 v = buf[i % 12];
            if (i < 84) buf[i % 12] = base[(size_t)(i + 12) * 256];
            float u = su[i], vb = sv[i];
            accR.x += v.x * u;  accR.y += v.y * u;  accR.z += v.z * u;  accR.w += v.w * u;
            accS.x += v.x * vb; accS.y += v.y * vb; accS.z += v.z * vb; accS.w += v.w * vb;
        }
        // private dots complete: direct coalesced store
        ((float4*)(ws + OFF_SR))[slice * (NS/4) + b * 256 + t] = accR;
        ((float4*)(ws + OFF_SS))[slice * (NS/4) + b * 256 + t] = accS;
    } else {
        int f = t & 63, cg = t >> 6;      // pixel-quad, channel-group
        const float4* base = (const float4*)tf + ((size_t)b * DD + slice * 384) * (NTP/4) + t;
        float4 buf[12];
        #pragma unroll
        for (int k = 0; k < 12; ++k) buf[k] = base[(size_t)k * 256];
        #pragma unroll
        for (int i = 0; i < 96; ++i) {
            float4 v = buf[i % 12];
            if (i < 84) buf[i % 12] = base[(size_t)(i + 12) * 256];
            float u = su[cg + 4 * i], vb = sv[cg + 4 * i];
            accR.x += v.x * u;  accR.y += v.y * u;  accR.z += v.z * u;  accR.w += v.w * u;
            accS.x += v.x * vb; accS.y += v.y * vb; accS.z += v.z * vb; accS.w += v.w * vb;
        }
        __shared__ float4 redR[4][64], redS[4][64];
        redR[cg][f] = accR; redS[cg][f] = accS;
        __syncthreads();
        if (cg < 2) {
            float4 a = redR[cg + 2][f], m = redR[cg][f];
            m.x += a.x; m.y += a.y; m.z += a.z; m.w += a.w; redR[cg][f] = m;
            float4 c = redS[cg + 2][f], n = redS[cg][f];
            n.x += c.x; n.y += c.y; n.z += c.z; n.w += c.w; redS[cg][f] = n;
        }
        __syncthreads();
        if (cg == 0) {
            float4 a = redR[1][f], m = redR[0][f];
            m.x += a.x; m.y += a.y; m.z += a.z; m.w += a.w;
            float4 c = redS[1][f], n = redS[0][f];
            n.x += c.x; n.y += c.y; n.z += c.z; n.w += c.w;
            ((float4*)(ws + OFF_TR0))[slice * (NT/4) + b * 64 + f] = m;
            ((float4*)(ws + OFF_TS0))[slice * (NT/4) + b * 64 + f] = n;
        }
    }
}

// Per batch: filter iterations from target dots (2 slices), then final output
// combine (8 search slices, 4 px per thread).
__global__ void k_final(const float* __restrict__ mask, const float* __restrict__ ws,
                        float* __restrict__ out) {
    int b = blockIdx.x;
    int p = threadIdx.x;
    int lane = p & 63, wv = p >> 6;
    int h = p >> 4, w = p & 15;
    float K1 = ws[OFF_K], K2 = ws[OFF_K + 1];
    float r0 = K1 + ws[OFF_TR0 + b * 256 + p] + ws[OFF_TR0 + NT + b * 256 + p];
    float s0 = K2 + ws[OFF_TS0 + b * 256 + p] + ws[OFF_TS0 + NT + b * 256 + p];
    float m = mask[b * 256 + p];
    __shared__ float cross[4];
    auto bsum = [&](float v) -> float {
        #pragma unroll
        for (int o = 32; o > 0; o >>= 1) v += __shfl_xor(v, o, 64);
        if (lane == 0) cross[wv] = v;
        __syncthreads();
        float r = cross[0] + cross[1] + cross[2] + cross[3];
        __syncthreads();
        return r;
    };
    float msum = bsum(m);
    float sy = bsum(m * (float)h);
    float sx = bsum(m * (float)w);
    msum = fmaxf(msum, 1.0f);
    float cy = sy / msum, cx = sx / msum;
    float dx = (float)w - cx, dy = (float)h - cy;
    float label = expf(-(dx * dx + dy * dy) * 0.125f);   // 2*sigma^2 = 8
    float A = 1.0f, c = 0.0f;
    const float decay = 1.0f - 0.1f * 0.01f;
    #pragma unroll
    for (int it = 0; it < 5; ++it) {
        float resp = A * r0 + c * s0;
        float gc = (1.0f - resp * label > 0.0f) ? (-label * m) : 0.0f;
        float g = bsum(gc) * (1.0f / 256.0f);
        c = decay * c - 0.1f * g;
        A *= decay;
    }
    // combine: 4 search px per thread
    int g4 = b * 256 + p;                 // f4 index into [NS/4]
    float4 R = {K1, K1, K1, K1}, S = {K2, K2, K2, K2};
    #pragma unroll
    for (int o = 0; o < NSL; ++o) {
        float4 a = ((const float4*)(ws + OFF_SR))[o * (NS/4) + g4];
        float4 d = ((const float4*)(ws + OFF_SS))[o * (NS/4) + g4];
        R.x += a.x; R.y += a.y; R.z += a.z; R.w += a.w;
        S.x += d.x; S.y += d.y; S.z += d.z; S.w += d.w;
    }
    float4 o;
    o.x = A5 * R.x + c * S.x;
    o.y = A5 * R.y + c * S.y;
    o.z = A5 * R.z + c * S.z;
    o.w = A5 * R.w + c * S.w;
    ((float4*)out)[g4] = o;
}

extern "C" void kernel_launch(void* const* d_in, const int* in_sizes, int n_in,
                              void* d_out, int out_size, void* d_ws, size_t ws_size,
                              hipStream_t stream) {
    const float* sf    = (const float*)d_in[0];
    const float* tf    = (const float*)d_in[1];
    const float* mask  = (const float*)d_in[2];
    const float* w     = (const float*)d_in[3];
    const float* cb    = (const float*)d_in[4];
    const float* gamma = (const float*)d_in[5];
    const float* beta  = (const float*)d_in[6];
    const float* mean  = (const float*)d_in[7];
    const float* var   = (const float*)d_in[8];
    const float* fi    = (const float*)d_in[9];
    float* out = (float*)d_out;
    float* ws  = (float*)d_ws;

    k_prep <<<ECH + 1, 256, 0, stream>>>(w, cb, gamma, beta, mean, var, fi, ws);
    k_big  <<<320,     256, 0, stream>>>(sf, tf, ws);
    k_final<<<BB,      256, 0, stream>>>(mask, ws, out);
}